// Round 1
// baseline (1809.754 us; speedup 1.0000x reference)
//
#include <hip/hip_runtime.h>
#include <cstdint>
#include <cstddef>

#define HIDS 1024
#define NHEAD 16
#define HDIM 64
#define LSEQ 2048
#define BBATCH 2
#define NROW (BBATCH * LSEQ)  // 4096

// ---------------------------------------------------------------------------
// GEMM: C[M,N] = A[M,K] @ B[K,N], all row-major, M,N multiples of 64, K of 16
// 64x64 tile, 256 threads, 4x4 accumulator per thread, LDS-staged, reg prefetch
// ---------------------------------------------------------------------------
__global__ __launch_bounds__(256) void gemm64(const float* __restrict__ A,
                                              const float* __restrict__ B,
                                              float* __restrict__ C,
                                              int M, int N, int K) {
  __shared__ float As[16][68];  // [k][m], ld 68 keeps 16B align + 2-way-max conflicts
  __shared__ float Bs[16][64];  // [k][n]
  const int tid = threadIdx.x;
  const int tx = tid & 15, ty = tid >> 4;
  const int bm = blockIdx.y * 64, bn = blockIdx.x * 64;
  // A-tile load: thread -> row lar (0..63), k offset lac (0,4,8,12)
  const int lar = tid >> 2, lac = (tid & 3) * 4;
  // B-tile load: thread -> k row lbr (0..15), col lbc (0..60 step 4)
  const int lbr = tid >> 4, lbc = (tid & 15) * 4;
  const float* Ap = A + (size_t)(bm + lar) * K + lac;
  const float* Bp = B + (size_t)lbr * N + bn + lbc;

  float4 av = *(const float4*)Ap;
  float4 bv = *(const float4*)Bp;
  float acc[4][4] = {};

  for (int k0 = 0; k0 < K; k0 += 16) {
    __syncthreads();
    As[lac + 0][lar] = av.x;
    As[lac + 1][lar] = av.y;
    As[lac + 2][lar] = av.z;
    As[lac + 3][lar] = av.w;
    *(float4*)&Bs[lbr][lbc] = bv;
    __syncthreads();
    if (k0 + 16 < K) {  // prefetch next K-tile into registers during compute
      av = *(const float4*)(Ap + k0 + 16);
      bv = *(const float4*)(Bp + (size_t)(k0 + 16) * N);
    }
#pragma unroll
    for (int kk = 0; kk < 16; ++kk) {
      float4 a4 = *(const float4*)&As[kk][ty * 4];
      float4 b4 = *(const float4*)&Bs[kk][tx * 4];
      float ar[4] = {a4.x, a4.y, a4.z, a4.w};
      float br[4] = {b4.x, b4.y, b4.z, b4.w};
#pragma unroll
      for (int i = 0; i < 4; ++i)
#pragma unroll
        for (int j = 0; j < 4; ++j) acc[i][j] = fmaf(ar[i], br[j], acc[i][j]);
    }
  }
#pragma unroll
  for (int i = 0; i < 4; ++i) {
    float4 o = make_float4(acc[i][0], acc[i][1], acc[i][2], acc[i][3]);
    *(float4*)(C + (size_t)(bm + ty * 4 + i) * N + bn + tx * 4) = o;
  }
}

// ---------------------------------------------------------------------------
// gate = exp(log_sigmoid((x @ Wgk1) @ Wgk2 + bgk2) / 16)   [NROW, HIDS]
// one block per row
// ---------------------------------------------------------------------------
__global__ __launch_bounds__(256) void gate_kernel(const float* __restrict__ x,
                                                   const float* __restrict__ Wgk1,
                                                   const float* __restrict__ Wgk2,
                                                   const float* __restrict__ bgk2,
                                                   float* __restrict__ gate) {
  const int row = blockIdx.x;
  const int tid = threadIdx.x;
  __shared__ float xl[16];
  __shared__ float part[16][17];
  const int c = tid & 15, ks = tid >> 4;  // both 0..15
  const float* xr = x + (size_t)row * HIDS;
  float p = 0.f;
#pragma unroll 4
  for (int i = 0; i < 64; ++i) {
    int k = ks + i * 16;
    p = fmaf(xr[k], Wgk1[k * 16 + c], p);
  }
  part[ks][c] = p;
  __syncthreads();
  if (tid < 16) {
    float s = 0.f;
#pragma unroll
    for (int i = 0; i < 16; ++i) s += part[i][tid];
    xl[tid] = s;
  }
  __syncthreads();
#pragma unroll
  for (int jj = 0; jj < 4; ++jj) {
    int col = tid + jj * 256;
    float z = bgk2[col];
#pragma unroll
    for (int r = 0; r < 16; ++r) z = fmaf(xl[r], Wgk2[r * HIDS + col], z);
    // stable log_sigmoid
    float ls = fminf(z, 0.f) - log1pf(expf(-fabsf(z)));
    gate[(size_t)row * HIDS + col] = expf(ls * (1.f / 16.f));
  }
}

// ---------------------------------------------------------------------------
// Sequential gated scan. One block per (b,h). 256 threads.
// thread: v = tid>>2 (0..63), k-slice = (tid&3)*16 .. +16 ; 16 state regs.
// ---------------------------------------------------------------------------
__global__ __launch_bounds__(256) void scan_kernel(const float* __restrict__ q,
                                                   const float* __restrict__ k,
                                                   const float* __restrict__ v,
                                                   const float* __restrict__ gate,
                                                   float* __restrict__ att) {
  const int b = blockIdx.x >> 4;
  const int h = blockIdx.x & 15;
  const int tid = threadIdx.x;
  const int vv = tid >> 2;
  const int kg = (tid & 3) * 16;
  __shared__ float sq[64], sk[64], sv[64], sg[64];
  const size_t base = ((size_t)b * LSEQ) * HIDS + h * HDIM;

  const int which = tid >> 6, j = tid & 63;
  const float* sp = (which == 0) ? q : (which == 1) ? k : (which == 2) ? v : gate;
  float* dp = (which == 0) ? sq : (which == 1) ? sk : (which == 2) ? sv : sg;
  const float* myp = sp + base + j;
  float* myd = dp + j;

  float st[16];
#pragma unroll
  for (int i = 0; i < 16; ++i) st[i] = 0.f;

  float pre = myp[0];  // t = 0
  for (int t = 0; t < LSEQ; ++t) {
    __syncthreads();
    *myd = pre;
    __syncthreads();
    if (t + 1 < LSEQ) pre = myp[(size_t)(t + 1) * HIDS];  // prefetch next step
    const float gt = sg[vv];
    const float vt = sv[vv];
    float sum = 0.f;
#pragma unroll
    for (int i = 0; i < 16; ++i) {
      st[i] = fmaf(st[i], gt, vt * sk[kg + i]);
      sum = fmaf(st[i], sq[kg + i], sum);
    }
    sum += __shfl_xor(sum, 1);
    sum += __shfl_xor(sum, 2);
    if ((tid & 3) == 0) att[base + (size_t)t * HIDS + vv] = sum;
  }
}

// ---------------------------------------------------------------------------
// y = LayerNorm(att) * gamma + beta, then * silu(g).  One block per row.
// ---------------------------------------------------------------------------
__global__ __launch_bounds__(256) void ln_gate_kernel(const float* __restrict__ att,
                                                      const float* __restrict__ g,
                                                      const float* __restrict__ gamma,
                                                      const float* __restrict__ beta,
                                                      float* __restrict__ y) {
  const int row = blockIdx.x;
  const int tid = threadIdx.x;
  const float* ar = att + (size_t)row * HIDS;
  float4 a = *(const float4*)(ar + tid * 4);
  float s = a.x + a.y + a.z + a.w;
  float ss = a.x * a.x + a.y * a.y + a.z * a.z + a.w * a.w;
#pragma unroll
  for (int off = 32; off; off >>= 1) {
    s += __shfl_down(s, off);
    ss += __shfl_down(ss, off);
  }
  __shared__ float rs[4], rss[4];
  const int wid = tid >> 6;
  if ((tid & 63) == 0) { rs[wid] = s; rss[wid] = ss; }
  __syncthreads();
  const float mean = (rs[0] + rs[1] + rs[2] + rs[3]) * (1.f / HIDS);
  const float ex2 = (rss[0] + rss[1] + rss[2] + rss[3]) * (1.f / HIDS);
  const float rstd = rsqrtf(ex2 - mean * mean + 1e-5f);

  float4 ga = *(const float4*)(gamma + tid * 4);
  float4 be = *(const float4*)(beta + tid * 4);
  float4 gv = *(const float4*)(g + (size_t)row * HIDS + tid * 4);
  float4 o;
  o.x = ((a.x - mean) * rstd * ga.x + be.x) * (gv.x / (1.f + expf(-gv.x)));
  o.y = ((a.y - mean) * rstd * ga.y + be.y) * (gv.y / (1.f + expf(-gv.y)));
  o.z = ((a.z - mean) * rstd * ga.z + be.z) * (gv.z / (1.f + expf(-gv.z)));
  o.w = ((a.w - mean) * rstd * ga.w + be.w) * (gv.w / (1.f + expf(-gv.w)));
  *(float4*)(y + (size_t)row * HIDS + tid * 4) = o;
}

// ---------------------------------------------------------------------------
extern "C" void kernel_launch(void* const* d_in, const int* in_sizes, int n_in,
                              void* d_out, int out_size, void* d_ws, size_t ws_size,
                              hipStream_t stream) {
  const float* x     = (const float*)d_in[0];
  const float* Wq    = (const float*)d_in[1];
  const float* Wk    = (const float*)d_in[2];
  const float* Wv    = (const float*)d_in[3];
  const float* Wg    = (const float*)d_in[4];
  const float* Wgk1  = (const float*)d_in[5];
  const float* Wgk2  = (const float*)d_in[6];
  const float* bgk2  = (const float*)d_in[7];
  const float* gamma = (const float*)d_in[8];
  const float* beta  = (const float*)d_in[9];
  const float* Wout  = (const float*)d_in[10];
  float* out = (float*)d_out;

  const size_t SZ = (size_t)NROW * HIDS;  // 4M floats
  float* ws = (float*)d_ws;
  float* qb    = ws;
  float* kb    = ws + SZ;
  float* vb    = ws + 2 * SZ;
  float* gb    = ws + 3 * SZ;
  float* gateb = ws + 4 * SZ;
  float* attb  = ws + 5 * SZ;
  float* yb    = qb;  // q is dead after the scan; reuse its buffer for y

  dim3 gg(HIDS / 64, NROW / 64);  // 16 x 64
  gemm64<<<gg, 256, 0, stream>>>(x, Wq, qb, NROW, HIDS, HIDS);
  gemm64<<<gg, 256, 0, stream>>>(x, Wk, kb, NROW, HIDS, HIDS);
  gemm64<<<gg, 256, 0, stream>>>(x, Wv, vb, NROW, HIDS, HIDS);
  gemm64<<<gg, 256, 0, stream>>>(x, Wg, gb, NROW, HIDS, HIDS);
  gate_kernel<<<NROW, 256, 0, stream>>>(x, Wgk1, Wgk2, bgk2, gateb);
  scan_kernel<<<BBATCH * NHEAD, 256, 0, stream>>>(qb, kb, vb, gateb, attb);
  ln_gate_kernel<<<NROW, 256, 0, stream>>>(attb, gb, gamma, beta, yb);
  gemm64<<<gg, 256, 0, stream>>>(yb, Wout, out, NROW, HIDS, HIDS);
}

// Round 2
// 788.840 us; speedup vs baseline: 2.2942x; 2.2942x over previous
//
#include <hip/hip_runtime.h>
#include <cstdint>
#include <cstddef>

#define HIDS 1024
#define NHEAD 16
#define HDIM 64
#define LSEQ 2048
#define BBATCH 2
#define NROW (BBATCH * LSEQ)  // 4096
#define CHUNK 64
#define NCHUNK (LSEQ / CHUNK)  // 32

// ---------------------------------------------------------------------------
// GEMM: C[M,N] = A[M,K] @ B[K,N], row-major. 64x64 tile, 256 thr, 4x4 acc.
// ---------------------------------------------------------------------------
__global__ __launch_bounds__(256) void gemm64(const float* __restrict__ A,
                                              const float* __restrict__ B,
                                              float* __restrict__ C,
                                              int M, int N, int K) {
  __shared__ float As[16][68];
  __shared__ float Bs[16][64];
  const int tid = threadIdx.x;
  const int tx = tid & 15, ty = tid >> 4;
  const int bm = blockIdx.y * 64, bn = blockIdx.x * 64;
  const int lar = tid >> 2, lac = (tid & 3) * 4;
  const int lbr = tid >> 4, lbc = (tid & 15) * 4;
  const float* Ap = A + (size_t)(bm + lar) * K + lac;
  const float* Bp = B + (size_t)lbr * N + bn + lbc;

  float4 av = *(const float4*)Ap;
  float4 bv = *(const float4*)Bp;
  float acc[4][4] = {};

  for (int k0 = 0; k0 < K; k0 += 16) {
    __syncthreads();
    As[lac + 0][lar] = av.x;
    As[lac + 1][lar] = av.y;
    As[lac + 2][lar] = av.z;
    As[lac + 3][lar] = av.w;
    *(float4*)&Bs[lbr][lbc] = bv;
    __syncthreads();
    if (k0 + 16 < K) {
      av = *(const float4*)(Ap + k0 + 16);
      bv = *(const float4*)(Bp + (size_t)(k0 + 16) * N);
    }
#pragma unroll
    for (int kk = 0; kk < 16; ++kk) {
      float4 a4 = *(const float4*)&As[kk][ty * 4];
      float4 b4 = *(const float4*)&Bs[kk][tx * 4];
      float ar[4] = {a4.x, a4.y, a4.z, a4.w};
      float br[4] = {b4.x, b4.y, b4.z, b4.w};
#pragma unroll
      for (int i = 0; i < 4; ++i)
#pragma unroll
        for (int j = 0; j < 4; ++j) acc[i][j] = fmaf(ar[i], br[j], acc[i][j]);
    }
  }
#pragma unroll
  for (int i = 0; i < 4; ++i) {
    float4 o = make_float4(acc[i][0], acc[i][1], acc[i][2], acc[i][3]);
    *(float4*)(C + (size_t)(bm + ty * 4 + i) * N + bn + tx * 4) = o;
  }
}

// ---------------------------------------------------------------------------
// logg = log_sigmoid((x @ Wgk1) @ Wgk2 + bgk2) / 16      (LOG gate, for cumsum)
// ---------------------------------------------------------------------------
__global__ __launch_bounds__(256) void gate_kernel(const float* __restrict__ x,
                                                   const float* __restrict__ Wgk1,
                                                   const float* __restrict__ Wgk2,
                                                   const float* __restrict__ bgk2,
                                                   float* __restrict__ logg) {
  const int row = blockIdx.x;
  const int tid = threadIdx.x;
  __shared__ float xl[16];
  __shared__ float part[16][17];
  const int c = tid & 15, ks = tid >> 4;
  const float* xr = x + (size_t)row * HIDS;
  float p = 0.f;
#pragma unroll 4
  for (int i = 0; i < 64; ++i) {
    int k = ks + i * 16;
    p = fmaf(xr[k], Wgk1[k * 16 + c], p);
  }
  part[ks][c] = p;
  __syncthreads();
  if (tid < 16) {
    float s = 0.f;
#pragma unroll
    for (int i = 0; i < 16; ++i) s += part[i][tid];
    xl[tid] = s;
  }
  __syncthreads();
#pragma unroll
  for (int jj = 0; jj < 4; ++jj) {
    int col = tid + jj * 256;
    float z = bgk2[col];
#pragma unroll
    for (int r = 0; r < 16; ++r) z = fmaf(xl[r], Wgk2[r * HIDS + col], z);
    float ls = fminf(z, 0.f) - log1pf(expf(-fabsf(z)));
    logg[(size_t)row * HIDS + col] = ls * (1.f / 16.f);
  }
}

// ---------------------------------------------------------------------------
// Phase 1: per (b,h,chunk): cumulative gates, A=tril(QK^T),
//   out_intra = e^G * (A @ (e^-G * V)), Sdelta = Lam * (Vt^T K), Lam = e^G_63.
// Also overwrites `gate` global with E = e^Gamma for phase 2b.
// ---------------------------------------------------------------------------
__global__ __launch_bounds__(256) void chunk_local_kernel(
    const float* __restrict__ q, const float* __restrict__ k,
    const float* __restrict__ v, float* __restrict__ gate,
    float* __restrict__ att, float* __restrict__ Sdelta,
    float* __restrict__ Lam) {
  const int bid = blockIdx.x;           // 0..1023
  const int c = bid & 31, bh = bid >> 5;
  const int b = bh >> 4, h = bh & 15;
  const int tid = threadIdx.x;
  const int tx = tid & 15, ty = tid >> 4;

  __shared__ float sQ[64][65];  // Q, then reused as A
  __shared__ float sK[64][65];
  __shared__ float sV[64][65];  // becomes e^{-Gamma} * V
  __shared__ float sG[64][65];  // becomes Gamma (inclusive cumsum)

  const size_t base = ((size_t)b * LSEQ + (size_t)c * CHUNK) * HIDS + (size_t)h * HDIM;

#pragma unroll
  for (int i = 0; i < 4; ++i) {
    int r = ty + 16 * i;
    int cc = tx * 4;
    const size_t g0 = base + (size_t)r * HIDS + cc;
    float4 qq = *(const float4*)(q + g0);
    float4 kk = *(const float4*)(k + g0);
    float4 vv = *(const float4*)(v + g0);
    float4 gg = *(const float4*)(gate + g0);
    sQ[r][cc] = qq.x; sQ[r][cc + 1] = qq.y; sQ[r][cc + 2] = qq.z; sQ[r][cc + 3] = qq.w;
    sK[r][cc] = kk.x; sK[r][cc + 1] = kk.y; sK[r][cc + 2] = kk.z; sK[r][cc + 3] = kk.w;
    sV[r][cc] = vv.x; sV[r][cc + 1] = vv.y; sV[r][cc + 2] = vv.z; sV[r][cc + 3] = vv.w;
    sG[r][cc] = gg.x; sG[r][cc + 1] = gg.y; sG[r][cc + 2] = gg.z; sG[r][cc + 3] = gg.w;
  }
  __syncthreads();

  // inclusive cumsum of sG along t (per v column): 2-level scan
  const int vcol = tid & 63, qtr = tid >> 6;
  {
    float run = 0.f;
#pragma unroll
    for (int i = 0; i < 16; ++i) {
      run += sG[qtr * 16 + i][vcol];
      sG[qtr * 16 + i][vcol] = run;
    }
  }
  __syncthreads();
  float pre = 0.f;
  for (int j = 0; j < qtr; ++j) pre += sG[j * 16 + 15][vcol];
  __syncthreads();
#pragma unroll
  for (int i = 0; i < 16; ++i) {
    float gam = sG[qtr * 16 + i][vcol] + pre;
    sG[qtr * 16 + i][vcol] = gam;
    sV[qtr * 16 + i][vcol] *= expf(-gam);
  }
  __syncthreads();

  // A = tril(Q K^T), computed to regs then written into sQ space
  {
    float a[4][4] = {};
#pragma unroll
    for (int kk = 0; kk < 64; ++kk) {
      float ar[4], br[4];
#pragma unroll
      for (int i = 0; i < 4; ++i) ar[i] = sQ[ty * 4 + i][kk];
#pragma unroll
      for (int j = 0; j < 4; ++j) br[j] = sK[tx * 4 + j][kk];
#pragma unroll
      for (int i = 0; i < 4; ++i)
#pragma unroll
        for (int j = 0; j < 4; ++j) a[i][j] = fmaf(ar[i], br[j], a[i][j]);
    }
    __syncthreads();
#pragma unroll
    for (int i = 0; i < 4; ++i)
#pragma unroll
      for (int j = 0; j < 4; ++j)
        sQ[ty * 4 + i][tx * 4 + j] = (tx * 4 + j <= ty * 4 + i) ? a[i][j] : 0.f;
    __syncthreads();
  }

  // out_intra[t,v] = e^{G[t,v]} * sum_s A[t,s] * sV[s,v]; also E = e^G to gate
  {
    float o[4][4] = {};
#pragma unroll
    for (int ss = 0; ss < 64; ++ss) {
      float ar[4], br[4];
#pragma unroll
      for (int i = 0; i < 4; ++i) ar[i] = sQ[ty * 4 + i][ss];
#pragma unroll
      for (int j = 0; j < 4; ++j) br[j] = sV[ss][tx * 4 + j];
#pragma unroll
      for (int i = 0; i < 4; ++i)
#pragma unroll
        for (int j = 0; j < 4; ++j) o[i][j] = fmaf(ar[i], br[j], o[i][j]);
    }
#pragma unroll
    for (int i = 0; i < 4; ++i) {
      int t = ty * 4 + i;
      float4 e4;
      e4.x = expf(sG[t][tx * 4 + 0]);
      e4.y = expf(sG[t][tx * 4 + 1]);
      e4.z = expf(sG[t][tx * 4 + 2]);
      e4.w = expf(sG[t][tx * 4 + 3]);
      float4 o4 = make_float4(o[i][0] * e4.x, o[i][1] * e4.y, o[i][2] * e4.z, o[i][3] * e4.w);
      const size_t g0 = base + (size_t)t * HIDS + tx * 4;
      *(float4*)(att + g0) = o4;
      *(float4*)(gate + g0) = e4;
    }
  }

  // Sdelta[v,k] = e^{G63[v]} * sum_s sV[s,v] * sK[s,k]
  {
    float d[4][4] = {};
#pragma unroll
    for (int ss = 0; ss < 64; ++ss) {
      float ar[4], br[4];
#pragma unroll
      for (int i = 0; i < 4; ++i) ar[i] = sV[ss][ty * 4 + i];
#pragma unroll
      for (int j = 0; j < 4; ++j) br[j] = sK[ss][tx * 4 + j];
#pragma unroll
      for (int i = 0; i < 4; ++i)
#pragma unroll
        for (int j = 0; j < 4; ++j) d[i][j] = fmaf(ar[i], br[j], d[i][j]);
    }
    const size_t sbase = ((size_t)(bh * NCHUNK + c)) * (HDIM * HDIM);
#pragma unroll
    for (int i = 0; i < 4; ++i) {
      float lam = expf(sG[63][ty * 4 + i]);
      float4 o4 = make_float4(d[i][0] * lam, d[i][1] * lam, d[i][2] * lam, d[i][3] * lam);
      *(float4*)(Sdelta + sbase + (size_t)(ty * 4 + i) * HDIM + tx * 4) = o4;
    }
    if (tid < 64) Lam[(size_t)(bh * NCHUNK + c) * HDIM + tid] = expf(sG[63][tid]);
  }
}

// ---------------------------------------------------------------------------
// Phase 2a: sequential over 32 chunk boundaries; 32 blocks, state in regs.
// Sprev[bh][c] = state BEFORE chunk c.
// ---------------------------------------------------------------------------
__global__ __launch_bounds__(256) void state_scan_kernel(
    const float* __restrict__ Sdelta, const float* __restrict__ Lam,
    float* __restrict__ Sprev) {
  const int bh = blockIdx.x;
  const int tid = threadIdx.x;
  float S[16];
#pragma unroll
  for (int i = 0; i < 16; ++i) S[i] = 0.f;

  float pd[16], pl[16];
  {
    const size_t base = (size_t)(bh * NCHUNK) * (HDIM * HDIM);
    const size_t lbase = (size_t)(bh * NCHUNK) * HDIM;
#pragma unroll
    for (int i = 0; i < 16; ++i) {
      int e = tid + 256 * i;
      pd[i] = Sdelta[base + e];
      pl[i] = Lam[lbase + (e >> 6)];
    }
  }
  for (int c = 0; c < NCHUNK; ++c) {
    float cd[16], cl[16];
#pragma unroll
    for (int i = 0; i < 16; ++i) { cd[i] = pd[i]; cl[i] = pl[i]; }
    if (c + 1 < NCHUNK) {
      const size_t base = (size_t)(bh * NCHUNK + c + 1) * (HDIM * HDIM);
      const size_t lbase = (size_t)(bh * NCHUNK + c + 1) * HDIM;
#pragma unroll
      for (int i = 0; i < 16; ++i) {
        int e = tid + 256 * i;
        pd[i] = Sdelta[base + e];
        pl[i] = Lam[lbase + (e >> 6)];
      }
    }
    const size_t obase = (size_t)(bh * NCHUNK + c) * (HDIM * HDIM);
#pragma unroll
    for (int i = 0; i < 16; ++i) {
      int e = tid + 256 * i;
      Sprev[obase + e] = S[i];
      S[i] = fmaf(S[i], cl[i], cd[i]);
    }
  }
}

// ---------------------------------------------------------------------------
// Phase 2b: att[t,v] += E[t,v] * sum_k q[t,k] * Sprev[v,k]
// ---------------------------------------------------------------------------
__global__ __launch_bounds__(256) void chunk_out_kernel(
    const float* __restrict__ q, const float* __restrict__ E,
    const float* __restrict__ Sprev, float* __restrict__ att) {
  const int bid = blockIdx.x;
  const int c = bid & 31, bh = bid >> 5;
  const int b = bh >> 4, h = bh & 15;
  const int tid = threadIdx.x;
  const int tx = tid & 15, ty = tid >> 4;

  __shared__ float sQ[64][65];
  __shared__ float sS[64][65];  // Sprev [v][k]

  const size_t base = ((size_t)b * LSEQ + (size_t)c * CHUNK) * HIDS + (size_t)h * HDIM;
  const size_t sbase = (size_t)(bh * NCHUNK + c) * (HDIM * HDIM);

#pragma unroll
  for (int i = 0; i < 4; ++i) {
    int r = ty + 16 * i;
    int cc = tx * 4;
    float4 qq = *(const float4*)(q + base + (size_t)r * HIDS + cc);
    float4 pp = *(const float4*)(Sprev + sbase + (size_t)r * HDIM + cc);
    sQ[r][cc] = qq.x; sQ[r][cc + 1] = qq.y; sQ[r][cc + 2] = qq.z; sQ[r][cc + 3] = qq.w;
    sS[r][cc] = pp.x; sS[r][cc + 1] = pp.y; sS[r][cc + 2] = pp.z; sS[r][cc + 3] = pp.w;
  }
  __syncthreads();

  float o[4][4] = {};
#pragma unroll
  for (int kk = 0; kk < 64; ++kk) {
    float ar[4], br[4];
#pragma unroll
    for (int i = 0; i < 4; ++i) ar[i] = sQ[ty * 4 + i][kk];
#pragma unroll
    for (int j = 0; j < 4; ++j) br[j] = sS[tx * 4 + j][kk];
#pragma unroll
    for (int i = 0; i < 4; ++i)
#pragma unroll
      for (int j = 0; j < 4; ++j) o[i][j] = fmaf(ar[i], br[j], o[i][j]);
  }
#pragma unroll
  for (int i = 0; i < 4; ++i) {
    int t = ty * 4 + i;
    const size_t g0 = base + (size_t)t * HIDS + tx * 4;
    float4 e4 = *(const float4*)(E + g0);
    float4 a4 = *(const float4*)(att + g0);
    a4.x = fmaf(o[i][0], e4.x, a4.x);
    a4.y = fmaf(o[i][1], e4.y, a4.y);
    a4.z = fmaf(o[i][2], e4.z, a4.z);
    a4.w = fmaf(o[i][3], e4.w, a4.w);
    *(float4*)(att + g0) = a4;
  }
}

// ---------------------------------------------------------------------------
// y = LayerNorm(att) * gamma + beta, then * silu(g).  One block per row.
// ---------------------------------------------------------------------------
__global__ __launch_bounds__(256) void ln_gate_kernel(const float* __restrict__ att,
                                                      const float* __restrict__ g,
                                                      const float* __restrict__ gamma,
                                                      const float* __restrict__ beta,
                                                      float* __restrict__ y) {
  const int row = blockIdx.x;
  const int tid = threadIdx.x;
  const float* ar = att + (size_t)row * HIDS;
  float4 a = *(const float4*)(ar + tid * 4);
  float s = a.x + a.y + a.z + a.w;
  float ss = a.x * a.x + a.y * a.y + a.z * a.z + a.w * a.w;
#pragma unroll
  for (int off = 32; off; off >>= 1) {
    s += __shfl_down(s, off);
    ss += __shfl_down(ss, off);
  }
  __shared__ float rs[4], rss[4];
  const int wid = tid >> 6;
  if ((tid & 63) == 0) { rs[wid] = s; rss[wid] = ss; }
  __syncthreads();
  const float mean = (rs[0] + rs[1] + rs[2] + rs[3]) * (1.f / HIDS);
  const float ex2 = (rss[0] + rss[1] + rss[2] + rss[3]) * (1.f / HIDS);
  const float rstd = rsqrtf(ex2 - mean * mean + 1e-5f);

  float4 ga = *(const float4*)(gamma + tid * 4);
  float4 be = *(const float4*)(beta + tid * 4);
  float4 gv = *(const float4*)(g + (size_t)row * HIDS + tid * 4);
  float4 o;
  o.x = ((a.x - mean) * rstd * ga.x + be.x) * (gv.x / (1.f + expf(-gv.x)));
  o.y = ((a.y - mean) * rstd * ga.y + be.y) * (gv.y / (1.f + expf(-gv.y)));
  o.z = ((a.z - mean) * rstd * ga.z + be.z) * (gv.z / (1.f + expf(-gv.z)));
  o.w = ((a.w - mean) * rstd * ga.w + be.w) * (gv.w / (1.f + expf(-gv.w)));
  *(float4*)(y + (size_t)row * HIDS + tid * 4) = o;
}

// ---------------------------------------------------------------------------
extern "C" void kernel_launch(void* const* d_in, const int* in_sizes, int n_in,
                              void* d_out, int out_size, void* d_ws, size_t ws_size,
                              hipStream_t stream) {
  const float* x     = (const float*)d_in[0];
  const float* Wq    = (const float*)d_in[1];
  const float* Wk    = (const float*)d_in[2];
  const float* Wv    = (const float*)d_in[3];
  const float* Wg    = (const float*)d_in[4];
  const float* Wgk1  = (const float*)d_in[5];
  const float* Wgk2  = (const float*)d_in[6];
  const float* bgk2  = (const float*)d_in[7];
  const float* gamma = (const float*)d_in[8];
  const float* beta  = (const float*)d_in[9];
  const float* Wout  = (const float*)d_in[10];
  float* out = (float*)d_out;

  const size_t SZ = (size_t)NROW * HIDS;  // 4M floats
  float* ws = (float*)d_ws;
  float* qb     = ws;
  float* kb     = ws + SZ;
  float* vb     = ws + 2 * SZ;
  float* gb     = ws + 3 * SZ;
  float* gateb  = ws + 4 * SZ;   // log-gate -> overwritten with e^Gamma
  float* attb   = ws + 5 * SZ;
  float* Sdelta = ws + 6 * SZ;   // [32bh][32c][64][64] = 4M floats
  float* Lamb   = ws + 7 * SZ;   // [32bh][32c][64] = 64K floats
  float* Sprev  = kb;            // kb dead after phase 1; reuse for boundary states
  float* yb     = vb;            // vb dead after phase 1; reuse for LN output

  dim3 gg(HIDS / 64, NROW / 64);  // 16 x 64
  gemm64<<<gg, 256, 0, stream>>>(x, Wq, qb, NROW, HIDS, HIDS);
  gemm64<<<gg, 256, 0, stream>>>(x, Wk, kb, NROW, HIDS, HIDS);
  gemm64<<<gg, 256, 0, stream>>>(x, Wv, vb, NROW, HIDS, HIDS);
  gemm64<<<gg, 256, 0, stream>>>(x, Wg, gb, NROW, HIDS, HIDS);
  gate_kernel<<<NROW, 256, 0, stream>>>(x, Wgk1, Wgk2, bgk2, gateb);

  chunk_local_kernel<<<BBATCH * NHEAD * NCHUNK, 256, 0, stream>>>(
      qb, kb, vb, gateb, attb, Sdelta, Lamb);
  state_scan_kernel<<<BBATCH * NHEAD, 256, 0, stream>>>(Sdelta, Lamb, Sprev);
  chunk_out_kernel<<<BBATCH * NHEAD * NCHUNK, 256, 0, stream>>>(
      qb, gateb, Sprev, attb);

  ln_gate_kernel<<<NROW, 256, 0, stream>>>(attb, gb, gamma, beta, yb);
  gemm64<<<gg, 256, 0, stream>>>(yb, Wout, out, NROW, HIDS, HIDS);
}

// Round 3
// 316.492 us; speedup vs baseline: 5.7182x; 2.4925x over previous
//
#include <hip/hip_runtime.h>
#include <cstdint>
#include <cstddef>

#define HIDS 1024
#define NHEAD 16
#define HDIM 64
#define LSEQ 2048
#define BBATCH 2
#define NROW (BBATCH * LSEQ)  // 4096
#define CHUNK 64
#define NCHUNK (LSEQ / CHUNK)  // 32

typedef short short8 __attribute__((ext_vector_type(8)));
typedef float floatx4 __attribute__((ext_vector_type(4)));

__device__ __forceinline__ ushort f2bf(float f) {
  uint32_t u = __float_as_uint(f);
  uint32_t r = (u + 0x7fffu + ((u >> 16) & 1u)) >> 16;  // RNE
  return (ushort)r;
}

__device__ __forceinline__ void async_copy16(const void* g, void* l) {
  __builtin_amdgcn_global_load_lds(
      (const __attribute__((address_space(1))) void*)g,
      (__attribute__((address_space(3))) void*)l, 16, 0, 0);
}

// ---------------------------------------------------------------------------
// x fp32 -> bf16 flat
// ---------------------------------------------------------------------------
__global__ __launch_bounds__(256) void cvt_x_kernel(const float* __restrict__ x,
                                                    ushort* __restrict__ xbf) {
  const int i = blockIdx.x * 256 + threadIdx.x;
  float4 f = *(const float4*)(x + (size_t)i * 4);
  ushort4 o;
  o.x = f2bf(f.x); o.y = f2bf(f.y); o.z = f2bf(f.z); o.w = f2bf(f.w);
  *(ushort4*)(xbf + (size_t)i * 4) = o;
}

// ---------------------------------------------------------------------------
// W [K=1024][N=1024] fp32 -> Wt [N][K] bf16, z selects one of 5 matrices
// ---------------------------------------------------------------------------
__global__ __launch_bounds__(256) void transpose_w_kernel(
    const float* __restrict__ W0, const float* __restrict__ W1,
    const float* __restrict__ W2, const float* __restrict__ W3,
    const float* __restrict__ W4, ushort* __restrict__ T0,
    ushort* __restrict__ T1, ushort* __restrict__ T2, ushort* __restrict__ T3,
    ushort* __restrict__ T4) {
  const int z = blockIdx.z;
  const float* W = (z == 0) ? W0 : (z == 1) ? W1 : (z == 2) ? W2 : (z == 3) ? W3 : W4;
  ushort* T = (z == 0) ? T0 : (z == 1) ? T1 : (z == 2) ? T2 : (z == 3) ? T3 : T4;
  __shared__ float sl[64][65];
  const int tid = threadIdx.x;
  const int k0 = blockIdx.y * 64, n0 = blockIdx.x * 64;
  const int r = tid >> 2, c4 = (tid & 3) * 16;
#pragma unroll
  for (int i = 0; i < 4; ++i) {
    float4 f = *(const float4*)(W + (size_t)(k0 + r) * HIDS + n0 + c4 + i * 4);
    sl[r][c4 + i * 4 + 0] = f.x;
    sl[r][c4 + i * 4 + 1] = f.y;
    sl[r][c4 + i * 4 + 2] = f.z;
    sl[r][c4 + i * 4 + 3] = f.w;
  }
  __syncthreads();
  const int n = tid >> 2, kc = (tid & 3) * 16;
#pragma unroll
  for (int i = 0; i < 4; ++i) {
    int kk = kc + i * 4;
    ushort4 o;
    o.x = f2bf(sl[kk + 0][n]);
    o.y = f2bf(sl[kk + 1][n]);
    o.z = f2bf(sl[kk + 2][n]);
    o.w = f2bf(sl[kk + 3][n]);
    *(ushort4*)(T + (size_t)(n0 + n) * HIDS + k0 + kk) = o;
  }
}

// ---------------------------------------------------------------------------
// bf16 MFMA GEMM (m97 structure): C[M,N] = A[M,K] @ Bt[N,K]^T, fp32 out.
// 128x128 tile, BK=32, 256 thr = 4 waves, 4x4 16x16x32 MFMA tiles per wave.
// ---------------------------------------------------------------------------
__device__ __forceinline__ void gemm_bf16_body(const ushort* __restrict__ A,
                                               const ushort* __restrict__ Bt,
                                               float* __restrict__ C,
                                               int bm, int bn, int K, int N) {
  __shared__ ushort As[128 * 32];
  __shared__ ushort Bs[128 * 32];
  const int tid = threadIdx.x;
  const int wave = tid >> 6, lane = tid & 63;
  const int wm = (wave >> 1) * 64, wn = (wave & 1) * 64;
  const int lrow = tid >> 2, lk8 = (tid & 3) * 8;
  const ushort* Ag = A + (size_t)(bm + lrow) * K + lk8;
  const ushort* Bg = Bt + (size_t)(bn + lrow) * K + lk8;
  char* AsB = (char*)As + tid * 16;
  char* BsB = (char*)Bs + tid * 16;

  floatx4 acc[4][4];
#pragma unroll
  for (int i = 0; i < 4; ++i)
#pragma unroll
    for (int j = 0; j < 4; ++j) acc[i][j] = (floatx4){0.f, 0.f, 0.f, 0.f};

  const int fm = lane & 15, quad = lane >> 4;

  for (int k0 = 0; k0 < K; k0 += 32) {
    __syncthreads();
    async_copy16(Ag + k0, AsB);
    async_copy16(Ag + (size_t)64 * K + k0, AsB + 4096);
    async_copy16(Bg + k0, BsB);
    async_copy16(Bg + (size_t)64 * K + k0, BsB + 4096);
    __syncthreads();

    short8 af[4], bfr[4];
#pragma unroll
    for (int i = 0; i < 4; ++i)
      af[i] = *(const short8*)&As[(wm + i * 16 + fm) * 32 + quad * 8];
#pragma unroll
    for (int j = 0; j < 4; ++j)
      bfr[j] = *(const short8*)&Bs[(wn + j * 16 + fm) * 32 + quad * 8];
#pragma unroll
    for (int i = 0; i < 4; ++i)
#pragma unroll
      for (int j = 0; j < 4; ++j)
        acc[i][j] = __builtin_amdgcn_mfma_f32_16x16x32_bf16(af[i], bfr[j],
                                                            acc[i][j], 0, 0, 0);
  }

#pragma unroll
  for (int i = 0; i < 4; ++i) {
    const int row0 = bm + wm + i * 16 + quad * 4;
#pragma unroll
    for (int j = 0; j < 4; ++j) {
      const int col = bn + wn + j * 16 + fm;
#pragma unroll
      for (int r = 0; r < 4; ++r)
        C[(size_t)(row0 + r) * N + col] = acc[i][j][r];
    }
  }
}

// 4 fused projections: z selects weight/output
__global__ __launch_bounds__(256) void proj4_kernel(
    const ushort* __restrict__ xbf, const ushort* __restrict__ Wtq,
    const ushort* __restrict__ Wtk, const ushort* __restrict__ Wtv,
    const ushort* __restrict__ Wtg, float* __restrict__ qb,
    float* __restrict__ kb, float* __restrict__ vb, float* __restrict__ gb) {
  const int z = blockIdx.z;
  const ushort* Bt = (z == 0) ? Wtq : (z == 1) ? Wtk : (z == 2) ? Wtv : Wtg;
  float* C = (z == 0) ? qb : (z == 1) ? kb : (z == 2) ? vb : gb;
  gemm_bf16_body(xbf, Bt, C, blockIdx.y * 128, blockIdx.x * 128, HIDS, HIDS);
}

__global__ __launch_bounds__(256) void gemm_out_kernel(
    const ushort* __restrict__ ybf, const ushort* __restrict__ Wto,
    float* __restrict__ C) {
  gemm_bf16_body(ybf, Wto, C, blockIdx.y * 128, blockIdx.x * 128, HIDS, HIDS);
}

// ---------------------------------------------------------------------------
// logg = log_sigmoid((x @ Wgk1) @ Wgk2 + bgk2) / 16      (LOG gate, for cumsum)
// ---------------------------------------------------------------------------
__global__ __launch_bounds__(256) void gate_kernel(const float* __restrict__ x,
                                                   const float* __restrict__ Wgk1,
                                                   const float* __restrict__ Wgk2,
                                                   const float* __restrict__ bgk2,
                                                   float* __restrict__ logg) {
  const int row = blockIdx.x;
  const int tid = threadIdx.x;
  __shared__ float xl[16];
  __shared__ float part[16][17];
  const int c = tid & 15, ks = tid >> 4;
  const float* xr = x + (size_t)row * HIDS;
  float p = 0.f;
#pragma unroll 4
  for (int i = 0; i < 64; ++i) {
    int k = ks + i * 16;
    p = fmaf(xr[k], Wgk1[k * 16 + c], p);
  }
  part[ks][c] = p;
  __syncthreads();
  if (tid < 16) {
    float s = 0.f;
#pragma unroll
    for (int i = 0; i < 16; ++i) s += part[i][tid];
    xl[tid] = s;
  }
  __syncthreads();
#pragma unroll
  for (int jj = 0; jj < 4; ++jj) {
    int col = tid + jj * 256;
    float z = bgk2[col];
#pragma unroll
    for (int r = 0; r < 16; ++r) z = fmaf(xl[r], Wgk2[r * HIDS + col], z);
    float ls = fminf(z, 0.f) - log1pf(expf(-fabsf(z)));
    logg[(size_t)row * HIDS + col] = ls * (1.f / 16.f);
  }
}

// ---------------------------------------------------------------------------
// Phase 1: per (b,h,chunk): cumulative gates, A=tril(QK^T),
//   out_intra = e^G * (A @ (e^-G * V)), Sdelta = Lam * (Vt^T K), Lam = e^G_63.
// Also overwrites `gate` global with E = e^Gamma for phase 2b.
// ---------------------------------------------------------------------------
__global__ __launch_bounds__(256) void chunk_local_kernel(
    const float* __restrict__ q, const float* __restrict__ k,
    const float* __restrict__ v, float* __restrict__ gate,
    float* __restrict__ att, float* __restrict__ Sdelta,
    float* __restrict__ Lam) {
  const int bid = blockIdx.x;           // 0..1023
  const int c = bid & 31, bh = bid >> 5;
  const int b = bh >> 4, h = bh & 15;
  const int tid = threadIdx.x;
  const int tx = tid & 15, ty = tid >> 4;

  __shared__ float sQ[64][65];  // Q, then reused as A
  __shared__ float sK[64][65];
  __shared__ float sV[64][65];  // becomes e^{-Gamma} * V
  __shared__ float sG[64][65];  // becomes Gamma (inclusive cumsum)

  const size_t base = ((size_t)b * LSEQ + (size_t)c * CHUNK) * HIDS + (size_t)h * HDIM;

#pragma unroll
  for (int i = 0; i < 4; ++i) {
    int r = ty + 16 * i;
    int cc = tx * 4;
    const size_t g0 = base + (size_t)r * HIDS + cc;
    float4 qq = *(const float4*)(q + g0);
    float4 kk = *(const float4*)(k + g0);
    float4 vv = *(const float4*)(v + g0);
    float4 gg = *(const float4*)(gate + g0);
    sQ[r][cc] = qq.x; sQ[r][cc + 1] = qq.y; sQ[r][cc + 2] = qq.z; sQ[r][cc + 3] = qq.w;
    sK[r][cc] = kk.x; sK[r][cc + 1] = kk.y; sK[r][cc + 2] = kk.z; sK[r][cc + 3] = kk.w;
    sV[r][cc] = vv.x; sV[r][cc + 1] = vv.y; sV[r][cc + 2] = vv.z; sV[r][cc + 3] = vv.w;
    sG[r][cc] = gg.x; sG[r][cc + 1] = gg.y; sG[r][cc + 2] = gg.z; sG[r][cc + 3] = gg.w;
  }
  __syncthreads();

  // inclusive cumsum of sG along t (per v column): 2-level scan
  const int vcol = tid & 63, qtr = tid >> 6;
  {
    float run = 0.f;
#pragma unroll
    for (int i = 0; i < 16; ++i) {
      run += sG[qtr * 16 + i][vcol];
      sG[qtr * 16 + i][vcol] = run;
    }
  }
  __syncthreads();
  float pre = 0.f;
  for (int j = 0; j < qtr; ++j) pre += sG[j * 16 + 15][vcol];
  __syncthreads();
#pragma unroll
  for (int i = 0; i < 16; ++i) {
    float gam = sG[qtr * 16 + i][vcol] + pre;
    sG[qtr * 16 + i][vcol] = gam;
    sV[qtr * 16 + i][vcol] *= expf(-gam);
  }
  __syncthreads();

  // A = tril(Q K^T)
  {
    float a[4][4] = {};
#pragma unroll
    for (int kk = 0; kk < 64; ++kk) {
      float ar[4], br[4];
#pragma unroll
      for (int i = 0; i < 4; ++i) ar[i] = sQ[ty * 4 + i][kk];
#pragma unroll
      for (int j = 0; j < 4; ++j) br[j] = sK[tx * 4 + j][kk];
#pragma unroll
      for (int i = 0; i < 4; ++i)
#pragma unroll
        for (int j = 0; j < 4; ++j) a[i][j] = fmaf(ar[i], br[j], a[i][j]);
    }
    __syncthreads();
#pragma unroll
    for (int i = 0; i < 4; ++i)
#pragma unroll
      for (int j = 0; j < 4; ++j)
        sQ[ty * 4 + i][tx * 4 + j] = (tx * 4 + j <= ty * 4 + i) ? a[i][j] : 0.f;
    __syncthreads();
  }

  // out_intra[t,v] = e^{G[t,v]} * sum_s A[t,s] * sV[s,v]; also E = e^G to gate
  {
    float o[4][4] = {};
#pragma unroll
    for (int ss = 0; ss < 64; ++ss) {
      float ar[4], br[4];
#pragma unroll
      for (int i = 0; i < 4; ++i) ar[i] = sQ[ty * 4 + i][ss];
#pragma unroll
      for (int j = 0; j < 4; ++j) br[j] = sV[ss][tx * 4 + j];
#pragma unroll
      for (int i = 0; i < 4; ++i)
#pragma unroll
        for (int j = 0; j < 4; ++j) o[i][j] = fmaf(ar[i], br[j], o[i][j]);
    }
#pragma unroll
    for (int i = 0; i < 4; ++i) {
      int t = ty * 4 + i;
      float4 e4;
      e4.x = expf(sG[t][tx * 4 + 0]);
      e4.y = expf(sG[t][tx * 4 + 1]);
      e4.z = expf(sG[t][tx * 4 + 2]);
      e4.w = expf(sG[t][tx * 4 + 3]);
      float4 o4 = make_float4(o[i][0] * e4.x, o[i][1] * e4.y, o[i][2] * e4.z, o[i][3] * e4.w);
      const size_t g0 = base + (size_t)t * HIDS + tx * 4;
      *(float4*)(att + g0) = o4;
      *(float4*)(gate + g0) = e4;
    }
  }

  // Sdelta[v,k] = e^{G63[v]} * sum_s sV[s,v] * sK[s,k]
  {
    float d[4][4] = {};
#pragma unroll
    for (int ss = 0; ss < 64; ++ss) {
      float ar[4], br[4];
#pragma unroll
      for (int i = 0; i < 4; ++i) ar[i] = sV[ss][ty * 4 + i];
#pragma unroll
      for (int j = 0; j < 4; ++j) br[j] = sK[ss][tx * 4 + j];
#pragma unroll
      for (int i = 0; i < 4; ++i)
#pragma unroll
        for (int j = 0; j < 4; ++j) d[i][j] = fmaf(ar[i], br[j], d[i][j]);
    }
    const size_t sbase = ((size_t)(bh * NCHUNK + c)) * (HDIM * HDIM);
#pragma unroll
    for (int i = 0; i < 4; ++i) {
      float lam = expf(sG[63][ty * 4 + i]);
      float4 o4 = make_float4(d[i][0] * lam, d[i][1] * lam, d[i][2] * lam, d[i][3] * lam);
      *(float4*)(Sdelta + sbase + (size_t)(ty * 4 + i) * HDIM + tx * 4) = o4;
    }
    if (tid < 64) Lam[(size_t)(bh * NCHUNK + c) * HDIM + tid] = expf(sG[63][tid]);
  }
}

// ---------------------------------------------------------------------------
// Phase 2a: sequential over 32 chunk boundaries; 32 blocks, state in regs.
// ---------------------------------------------------------------------------
__global__ __launch_bounds__(256) void state_scan_kernel(
    const float* __restrict__ Sdelta, const float* __restrict__ Lam,
    float* __restrict__ Sprev) {
  const int bh = blockIdx.x;
  const int tid = threadIdx.x;
  float S[16];
#pragma unroll
  for (int i = 0; i < 16; ++i) S[i] = 0.f;

  float pd[16], pl[16];
  {
    const size_t base = (size_t)(bh * NCHUNK) * (HDIM * HDIM);
    const size_t lbase = (size_t)(bh * NCHUNK) * HDIM;
#pragma unroll
    for (int i = 0; i < 16; ++i) {
      int e = tid + 256 * i;
      pd[i] = Sdelta[base + e];
      pl[i] = Lam[lbase + (e >> 6)];
    }
  }
  for (int c = 0; c < NCHUNK; ++c) {
    float cd[16], cl[16];
#pragma unroll
    for (int i = 0; i < 16; ++i) { cd[i] = pd[i]; cl[i] = pl[i]; }
    if (c + 1 < NCHUNK) {
      const size_t base = (size_t)(bh * NCHUNK + c + 1) * (HDIM * HDIM);
      const size_t lbase = (size_t)(bh * NCHUNK + c + 1) * HDIM;
#pragma unroll
      for (int i = 0; i < 16; ++i) {
        int e = tid + 256 * i;
        pd[i] = Sdelta[base + e];
        pl[i] = Lam[lbase + (e >> 6)];
      }
    }
    const size_t obase = (size_t)(bh * NCHUNK + c) * (HDIM * HDIM);
#pragma unroll
    for (int i = 0; i < 16; ++i) {
      int e = tid + 256 * i;
      Sprev[obase + e] = S[i];
      S[i] = fmaf(S[i], cl[i], cd[i]);
    }
  }
}

// ---------------------------------------------------------------------------
// Phase 2b: att[t,v] += E[t,v] * sum_k q[t,k] * Sprev[v,k]
// ---------------------------------------------------------------------------
__global__ __launch_bounds__(256) void chunk_out_kernel(
    const float* __restrict__ q, const float* __restrict__ E,
    const float* __restrict__ Sprev, float* __restrict__ att) {
  const int bid = blockIdx.x;
  const int c = bid & 31, bh = bid >> 5;
  const int b = bh >> 4, h = bh & 15;
  const int tid = threadIdx.x;
  const int tx = tid & 15, ty = tid >> 4;

  __shared__ float sQ[64][65];
  __shared__ float sS[64][65];  // Sprev [v][k]

  const size_t base = ((size_t)b * LSEQ + (size_t)c * CHUNK) * HIDS + (size_t)h * HDIM;
  const size_t sbase = (size_t)(bh * NCHUNK + c) * (HDIM * HDIM);

#pragma unroll
  for (int i = 0; i < 4; ++i) {
    int r = ty + 16 * i;
    int cc = tx * 4;
    float4 qq = *(const float4*)(q + base + (size_t)r * HIDS + cc);
    float4 pp = *(const float4*)(Sprev + sbase + (size_t)r * HDIM + cc);
    sQ[r][cc] = qq.x; sQ[r][cc + 1] = qq.y; sQ[r][cc + 2] = qq.z; sQ[r][cc + 3] = qq.w;
    sS[r][cc] = pp.x; sS[r][cc + 1] = pp.y; sS[r][cc + 2] = pp.z; sS[r][cc + 3] = pp.w;
  }
  __syncthreads();

  float o[4][4] = {};
#pragma unroll
  for (int kk = 0; kk < 64; ++kk) {
    float ar[4], br[4];
#pragma unroll
    for (int i = 0; i < 4; ++i) ar[i] = sQ[ty * 4 + i][kk];
#pragma unroll
    for (int j = 0; j < 4; ++j) br[j] = sS[tx * 4 + j][kk];
#pragma unroll
    for (int i = 0; i < 4; ++i)
#pragma unroll
      for (int j = 0; j < 4; ++j) o[i][j] = fmaf(ar[i], br[j], o[i][j]);
  }
#pragma unroll
  for (int i = 0; i < 4; ++i) {
    int t = ty * 4 + i;
    const size_t g0 = base + (size_t)t * HIDS + tx * 4;
    float4 e4 = *(const float4*)(E + g0);
    float4 a4 = *(const float4*)(att + g0);
    a4.x = fmaf(o[i][0], e4.x, a4.x);
    a4.y = fmaf(o[i][1], e4.y, a4.y);
    a4.z = fmaf(o[i][2], e4.z, a4.z);
    a4.w = fmaf(o[i][3], e4.w, a4.w);
    *(float4*)(att + g0) = a4;
  }
}

// ---------------------------------------------------------------------------
// y = (LayerNorm(att) * gamma + beta) * silu(g), written as bf16.
// ---------------------------------------------------------------------------
__global__ __launch_bounds__(256) void ln_gate_kernel(const float* __restrict__ att,
                                                      const float* __restrict__ g,
                                                      const float* __restrict__ gamma,
                                                      const float* __restrict__ beta,
                                                      ushort* __restrict__ ybf) {
  const int row = blockIdx.x;
  const int tid = threadIdx.x;
  const float* ar = att + (size_t)row * HIDS;
  float4 a = *(const float4*)(ar + tid * 4);
  float s = a.x + a.y + a.z + a.w;
  float ss = a.x * a.x + a.y * a.y + a.z * a.z + a.w * a.w;
#pragma unroll
  for (int off = 32; off; off >>= 1) {
    s += __shfl_down(s, off);
    ss += __shfl_down(ss, off);
  }
  __shared__ float rs[4], rss[4];
  const int wid = tid >> 6;
  if ((tid & 63) == 0) { rs[wid] = s; rss[wid] = ss; }
  __syncthreads();
  const float mean = (rs[0] + rs[1] + rs[2] + rs[3]) * (1.f / HIDS);
  const float ex2 = (rss[0] + rss[1] + rss[2] + rss[3]) * (1.f / HIDS);
  const float rstd = rsqrtf(ex2 - mean * mean + 1e-5f);

  float4 ga = *(const float4*)(gamma + tid * 4);
  float4 be = *(const float4*)(beta + tid * 4);
  float4 gv = *(const float4*)(g + (size_t)row * HIDS + tid * 4);
  float4 o;
  o.x = ((a.x - mean) * rstd * ga.x + be.x) * (gv.x / (1.f + expf(-gv.x)));
  o.y = ((a.y - mean) * rstd * ga.y + be.y) * (gv.y / (1.f + expf(-gv.y)));
  o.z = ((a.z - mean) * rstd * ga.z + be.z) * (gv.z / (1.f + expf(-gv.z)));
  o.w = ((a.w - mean) * rstd * ga.w + be.w) * (gv.w / (1.f + expf(-gv.w)));
  ushort4 ob;
  ob.x = f2bf(o.x); ob.y = f2bf(o.y); ob.z = f2bf(o.z); ob.w = f2bf(o.w);
  *(ushort4*)(ybf + (size_t)row * HIDS + tid * 4) = ob;
}

// ---------------------------------------------------------------------------
extern "C" void kernel_launch(void* const* d_in, const int* in_sizes, int n_in,
                              void* d_out, int out_size, void* d_ws, size_t ws_size,
                              hipStream_t stream) {
  const float* x     = (const float*)d_in[0];
  const float* Wq    = (const float*)d_in[1];
  const float* Wk    = (const float*)d_in[2];
  const float* Wv    = (const float*)d_in[3];
  const float* Wg    = (const float*)d_in[4];
  const float* Wgk1  = (const float*)d_in[5];
  const float* Wgk2  = (const float*)d_in[6];
  const float* bgk2  = (const float*)d_in[7];
  const float* gamma = (const float*)d_in[8];
  const float* beta  = (const float*)d_in[9];
  const float* Wout  = (const float*)d_in[10];
  float* out = (float*)d_out;

  const size_t SZ = (size_t)NROW * HIDS;  // 4M floats
  float* ws = (float*)d_ws;
  float* qb     = ws;
  float* kb     = ws + SZ;
  float* vb     = ws + 2 * SZ;
  float* gb     = ws + 3 * SZ;
  float* gateb  = ws + 4 * SZ;   // log-gate -> overwritten with e^Gamma
  float* attb   = ws + 5 * SZ;
  float* Sdelta = ws + 6 * SZ;   // 4M floats
  float* Lamb   = ws + 7 * SZ;   // 64K floats
  ushort* xbf   = (ushort*)(ws + 7 * SZ + 65536);      // 4M bf16
  ushort* Wtq   = xbf + SZ;                             // 5 x 1M bf16, [N][K]
  ushort* Wtk   = Wtq + HIDS * HIDS;
  ushort* Wtv   = Wtk + HIDS * HIDS;
  ushort* Wtg   = Wtv + HIDS * HIDS;
  ushort* Wto   = Wtg + HIDS * HIDS;
  float* Sprev  = kb;            // kb dead after chunk_local
  ushort* ybf   = (ushort*)vb;   // vb dead after chunk_local

  cvt_x_kernel<<<SZ / 1024, 256, 0, stream>>>(x, xbf);
  transpose_w_kernel<<<dim3(16, 16, 5), 256, 0, stream>>>(
      Wq, Wk, Wv, Wg, Wout, Wtq, Wtk, Wtv, Wtg, Wto);

  proj4_kernel<<<dim3(HIDS / 128, NROW / 128, 4), 256, 0, stream>>>(
      xbf, Wtq, Wtk, Wtv, Wtg, qb, kb, vb, gb);
  gate_kernel<<<NROW, 256, 0, stream>>>(x, Wgk1, Wgk2, bgk2, gateb);

  chunk_local_kernel<<<BBATCH * NHEAD * NCHUNK, 256, 0, stream>>>(
      qb, kb, vb, gateb, attb, Sdelta, Lamb);
  state_scan_kernel<<<BBATCH * NHEAD, 256, 0, stream>>>(Sdelta, Lamb, Sprev);
  chunk_out_kernel<<<BBATCH * NHEAD * NCHUNK, 256, 0, stream>>>(
      qb, gateb, Sprev, attb);

  ln_gate_kernel<<<NROW, 256, 0, stream>>>(attb, gb, gamma, beta, ybf);
  gemm_out_kernel<<<dim3(HIDS / 128, NROW / 128), 256, 0, stream>>>(ybf, Wto, out);
}

// Round 4
// 266.846 us; speedup vs baseline: 6.7820x; 1.1860x over previous
//
#include <hip/hip_runtime.h>
#include <cstdint>
#include <cstddef>

#define HIDS 1024
#define NHEAD 16
#define HDIM 64
#define LSEQ 2048
#define BBATCH 2
#define NROW (BBATCH * LSEQ)  // 4096
#define CHUNK 64
#define NCHUNK (LSEQ / CHUNK)  // 32

typedef short short8 __attribute__((ext_vector_type(8)));
typedef float floatx4 __attribute__((ext_vector_type(4)));

__device__ __forceinline__ ushort f2bf(float f) {
  uint32_t u = __float_as_uint(f);
  uint32_t r = (u + 0x7fffu + ((u >> 16) & 1u)) >> 16;  // RNE
  return (ushort)r;
}
__device__ __forceinline__ float bf2f(ushort u) {
  return __uint_as_float(((uint32_t)u) << 16);
}

__device__ __forceinline__ void async_copy16(const void* g, void* l) {
  __builtin_amdgcn_global_load_lds(
      (const __attribute__((address_space(1))) void*)g,
      (__attribute__((address_space(3))) void*)l, 16, 0, 0);
}

// ---------------------------------------------------------------------------
// x fp32 -> bf16 flat
// ---------------------------------------------------------------------------
__global__ __launch_bounds__(256) void cvt_x_kernel(const float* __restrict__ x,
                                                    ushort* __restrict__ xbf) {
  const int i = blockIdx.x * 256 + threadIdx.x;
  float4 f = *(const float4*)(x + (size_t)i * 4);
  ushort4 o;
  o.x = f2bf(f.x); o.y = f2bf(f.y); o.z = f2bf(f.z); o.w = f2bf(f.w);
  *(ushort4*)(xbf + (size_t)i * 4) = o;
}

// ---------------------------------------------------------------------------
// W [K][N] fp32 -> Wt [N][K] bf16, z selects one of 5 matrices
// ---------------------------------------------------------------------------
__global__ __launch_bounds__(256) void transpose_w_kernel(
    const float* __restrict__ W0, const float* __restrict__ W1,
    const float* __restrict__ W2, const float* __restrict__ W3,
    const float* __restrict__ W4, ushort* __restrict__ T0,
    ushort* __restrict__ T1, ushort* __restrict__ T2, ushort* __restrict__ T3,
    ushort* __restrict__ T4) {
  const int z = blockIdx.z;
  const float* W = (z == 0) ? W0 : (z == 1) ? W1 : (z == 2) ? W2 : (z == 3) ? W3 : W4;
  ushort* T = (z == 0) ? T0 : (z == 1) ? T1 : (z == 2) ? T2 : (z == 3) ? T3 : T4;
  __shared__ float sl[64][65];
  const int tid = threadIdx.x;
  const int k0 = blockIdx.y * 64, n0 = blockIdx.x * 64;
  const int r = tid >> 2, c4 = (tid & 3) * 16;
#pragma unroll
  for (int i = 0; i < 4; ++i) {
    float4 f = *(const float4*)(W + (size_t)(k0 + r) * HIDS + n0 + c4 + i * 4);
    sl[r][c4 + i * 4 + 0] = f.x;
    sl[r][c4 + i * 4 + 1] = f.y;
    sl[r][c4 + i * 4 + 2] = f.z;
    sl[r][c4 + i * 4 + 3] = f.w;
  }
  __syncthreads();
  const int n = tid >> 2, kc = (tid & 3) * 16;
#pragma unroll
  for (int i = 0; i < 4; ++i) {
    int kk = kc + i * 4;
    ushort4 o;
    o.x = f2bf(sl[kk + 0][n]);
    o.y = f2bf(sl[kk + 1][n]);
    o.z = f2bf(sl[kk + 2][n]);
    o.w = f2bf(sl[kk + 3][n]);
    *(ushort4*)(T + (size_t)(n0 + n) * HIDS + k0 + kk) = o;
  }
}

// ---------------------------------------------------------------------------
// bf16 MFMA GEMM, 128x128 tile, bf16 OUT: C = A[M,K] @ Bt[N,K]^T
// ---------------------------------------------------------------------------
__device__ __forceinline__ void gemm_bf16_body(const ushort* __restrict__ A,
                                               const ushort* __restrict__ Bt,
                                               ushort* __restrict__ C,
                                               int bm, int bn, int K, int N) {
  __shared__ ushort As[128 * 32];
  __shared__ ushort Bs[128 * 32];
  const int tid = threadIdx.x;
  const int wave = tid >> 6, lane = tid & 63;
  const int wm = (wave >> 1) * 64, wn = (wave & 1) * 64;
  const int lrow = tid >> 2, lk8 = (tid & 3) * 8;
  const ushort* Ag = A + (size_t)(bm + lrow) * K + lk8;
  const ushort* Bg = Bt + (size_t)(bn + lrow) * K + lk8;
  char* AsB = (char*)As + tid * 16;
  char* BsB = (char*)Bs + tid * 16;

  floatx4 acc[4][4];
#pragma unroll
  for (int i = 0; i < 4; ++i)
#pragma unroll
    for (int j = 0; j < 4; ++j) acc[i][j] = (floatx4){0.f, 0.f, 0.f, 0.f};

  const int fm = lane & 15, quad = lane >> 4;

  for (int k0 = 0; k0 < K; k0 += 32) {
    __syncthreads();
    async_copy16(Ag + k0, AsB);
    async_copy16(Ag + (size_t)64 * K + k0, AsB + 4096);
    async_copy16(Bg + k0, BsB);
    async_copy16(Bg + (size_t)64 * K + k0, BsB + 4096);
    __syncthreads();

    short8 af[4], bfr[4];
#pragma unroll
    for (int i = 0; i < 4; ++i)
      af[i] = *(const short8*)&As[(wm + i * 16 + fm) * 32 + quad * 8];
#pragma unroll
    for (int j = 0; j < 4; ++j)
      bfr[j] = *(const short8*)&Bs[(wn + j * 16 + fm) * 32 + quad * 8];
#pragma unroll
    for (int i = 0; i < 4; ++i)
#pragma unroll
      for (int j = 0; j < 4; ++j)
        acc[i][j] = __builtin_amdgcn_mfma_f32_16x16x32_bf16(af[i], bfr[j],
                                                            acc[i][j], 0, 0, 0);
  }

#pragma unroll
  for (int i = 0; i < 4; ++i) {
    const int row0 = bm + wm + i * 16 + quad * 4;
#pragma unroll
    for (int j = 0; j < 4; ++j) {
      const int col = bn + wn + j * 16 + fm;
#pragma unroll
      for (int r = 0; r < 4; ++r)
        C[(size_t)(row0 + r) * N + col] = f2bf(acc[i][j][r]);
    }
  }
}

// 4 fused projections (bf16 outputs)
__global__ __launch_bounds__(256) void proj4_kernel(
    const ushort* __restrict__ xbf, const ushort* __restrict__ Wtq,
    const ushort* __restrict__ Wtk, const ushort* __restrict__ Wtv,
    const ushort* __restrict__ Wtg, ushort* __restrict__ qb,
    ushort* __restrict__ kb, ushort* __restrict__ vb, ushort* __restrict__ gb) {
  const int z = blockIdx.z;
  const ushort* Bt = (z == 0) ? Wtq : (z == 1) ? Wtk : (z == 2) ? Wtv : Wtg;
  ushort* C = (z == 0) ? qb : (z == 1) ? kb : (z == 2) ? vb : gb;
  gemm_bf16_body(xbf, Bt, C, blockIdx.y * 128, blockIdx.x * 128, HIDS, HIDS);
}

// ---------------------------------------------------------------------------
// Output GEMM: 128(M) x 64(N) tile, fp32 out -> d_out. 512 blocks.
// ---------------------------------------------------------------------------
__global__ __launch_bounds__(256) void gemm_out_kernel(
    const ushort* __restrict__ A, const ushort* __restrict__ Bt,
    float* __restrict__ C) {
  __shared__ ushort As[128 * 32];
  __shared__ ushort Bs[64 * 32];
  const int tid = threadIdx.x;
  const int wave = tid >> 6, lane = tid & 63;
  const int fm = lane & 15, quad = lane >> 4;
  const int bm = blockIdx.y * 128, bn = blockIdx.x * 64;
  const int lrow = tid >> 2, lk8 = (tid & 3) * 8;
  const ushort* Ag = A + (size_t)(bm + lrow) * HIDS + lk8;
  const ushort* Bg = Bt + (size_t)(bn + lrow) * HIDS + lk8;
  char* AsB = (char*)As + tid * 16;
  char* BsB = (char*)Bs + tid * 16;

  floatx4 acc[2][4];
#pragma unroll
  for (int i = 0; i < 2; ++i)
#pragma unroll
    for (int j = 0; j < 4; ++j) acc[i][j] = (floatx4){0.f, 0.f, 0.f, 0.f};

  for (int k0 = 0; k0 < HIDS; k0 += 32) {
    __syncthreads();
    async_copy16(Ag + k0, AsB);
    async_copy16(Ag + (size_t)64 * HIDS + k0, AsB + 4096);
    async_copy16(Bg + k0, BsB);
    __syncthreads();

    short8 af[2], bfr[4];
#pragma unroll
    for (int i = 0; i < 2; ++i)
      af[i] = *(const short8*)&As[(wave * 32 + i * 16 + fm) * 32 + quad * 8];
#pragma unroll
    for (int j = 0; j < 4; ++j)
      bfr[j] = *(const short8*)&Bs[(j * 16 + fm) * 32 + quad * 8];
#pragma unroll
    for (int i = 0; i < 2; ++i)
#pragma unroll
      for (int j = 0; j < 4; ++j)
        acc[i][j] = __builtin_amdgcn_mfma_f32_16x16x32_bf16(af[i], bfr[j],
                                                            acc[i][j], 0, 0, 0);
  }

#pragma unroll
  for (int i = 0; i < 2; ++i) {
    const int row0 = bm + wave * 32 + i * 16 + quad * 4;
#pragma unroll
    for (int j = 0; j < 4; ++j) {
      const int col = bn + j * 16 + fm;
#pragma unroll
      for (int r = 0; r < 4; ++r)
        C[(size_t)(row0 + r) * HIDS + col] = acc[i][j][r];
    }
  }
}

// ---------------------------------------------------------------------------
// logg = log_sigmoid((x @ Wgk1) @ Wgk2 + bgk2) / 16
// ---------------------------------------------------------------------------
__global__ __launch_bounds__(256) void gate_kernel(const float* __restrict__ x,
                                                   const float* __restrict__ Wgk1,
                                                   const float* __restrict__ Wgk2,
                                                   const float* __restrict__ bgk2,
                                                   float* __restrict__ logg) {
  const int row = blockIdx.x;
  const int tid = threadIdx.x;
  __shared__ float xl[16];
  __shared__ float part[16][17];
  const int c = tid & 15, ks = tid >> 4;
  const float* xr = x + (size_t)row * HIDS;
  float p = 0.f;
#pragma unroll 4
  for (int i = 0; i < 64; ++i) {
    int k = ks + i * 16;
    p = fmaf(xr[k], Wgk1[k * 16 + c], p);
  }
  part[ks][c] = p;
  __syncthreads();
  if (tid < 16) {
    float s = 0.f;
#pragma unroll
    for (int i = 0; i < 16; ++i) s += part[i][tid];
    xl[tid] = s;
  }
  __syncthreads();
#pragma unroll
  for (int jj = 0; jj < 4; ++jj) {
    int col = tid + jj * 256;
    float z = bgk2[col];
#pragma unroll
    for (int r = 0; r < 16; ++r) z = fmaf(xl[r], Wgk2[r * HIDS + col], z);
    float ls = fminf(z, 0.f) - log1pf(expf(-fabsf(z)));
    logg[(size_t)row * HIDS + col] = ls * (1.f / 16.f);
  }
}

// ---------------------------------------------------------------------------
// Phase 1 (MFMA): per (b,h,chunk):
//   Gamma = cumsum(logg); Vt~ = (e^-Gamma V)^T; scores = tril(Q K^T);
//   att = e^Gamma . (scores @ V~); Sdelta = Lam . (V~^T K); E = e^Gamma -> gate
// ---------------------------------------------------------------------------
#define SP 72  // ushort stride for bf16 LDS tiles
#define SGS 68 // float stride for Gamma/E tile

__global__ __launch_bounds__(256) void chunk_local_kernel(
    const ushort* __restrict__ q, const ushort* __restrict__ k,
    const ushort* __restrict__ v, float* gate,
    float* __restrict__ att, float* __restrict__ Sdelta,
    float* __restrict__ Lam) {
  const int bid = blockIdx.x;
  const int c = bid & 31, bh = bid >> 5;
  const int b = bh >> 4, h = bh & 15;
  const int tid = threadIdx.x;
  const int lane = tid & 63, wave = tid >> 6;
  const int fm = lane & 15, quad = lane >> 4;
  const int wm2 = (wave >> 1) * 32, wn2 = (wave & 1) * 32;

  __shared__ ushort sQ[64 * SP];
  __shared__ ushort sK[64 * SP];
  __shared__ ushort sKt[64 * SP];
  __shared__ ushort sVt[64 * SP];
  __shared__ ushort sA[64 * SP];
  __shared__ float sG[64 * SGS];

  const size_t base = ((size_t)b * LSEQ + (size_t)c * CHUNK) * HIDS + (size_t)h * HDIM;
  const int r = tid >> 2, c0 = (tid & 3) * 16;
  const size_t gb = base + (size_t)r * HIDS + c0;

  short8 q0 = *(const short8*)(q + gb), q1 = *(const short8*)(q + gb + 8);
  short8 k0 = *(const short8*)(k + gb), k1 = *(const short8*)(k + gb + 8);
  short8 v0 = *(const short8*)(v + gb), v1 = *(const short8*)(v + gb + 8);
  float4 g0 = *(const float4*)(gate + gb);
  float4 g1 = *(const float4*)(gate + gb + 4);
  float4 g2 = *(const float4*)(gate + gb + 8);
  float4 g3 = *(const float4*)(gate + gb + 12);

  *(short8*)&sQ[r * SP + c0] = q0;
  *(short8*)&sQ[r * SP + c0 + 8] = q1;
  *(short8*)&sK[r * SP + c0] = k0;
  *(short8*)&sK[r * SP + c0 + 8] = k1;
  {
    const ushort* kp0 = (const ushort*)&k0;
    const ushort* kp1 = (const ushort*)&k1;
#pragma unroll
    for (int i = 0; i < 8; ++i) sKt[(c0 + i) * SP + r] = kp0[i];
#pragma unroll
    for (int i = 0; i < 8; ++i) sKt[(c0 + 8 + i) * SP + r] = kp1[i];
  }
  *(float4*)&sG[r * SGS + c0] = g0;
  *(float4*)&sG[r * SGS + c0 + 4] = g1;
  *(float4*)&sG[r * SGS + c0 + 8] = g2;
  *(float4*)&sG[r * SGS + c0 + 12] = g3;
  __syncthreads();

  // inclusive cumsum along t per v column (4 groups of 16 rows)
  const int vcol = tid & 63, qtr = tid >> 6;
  {
    float run = 0.f;
#pragma unroll
    for (int i = 0; i < 16; ++i) {
      int idx = (qtr * 16 + i) * SGS + vcol;
      run += sG[idx];
      sG[idx] = run;
    }
  }
  __syncthreads();
  float pre = 0.f;
  for (int j = 0; j < qtr; ++j) pre += sG[(j * 16 + 15) * SGS + vcol];
  __syncthreads();
#pragma unroll
  for (int i = 0; i < 16; ++i) sG[(qtr * 16 + i) * SGS + vcol] += pre;
  __syncthreads();

  // scale V, build sVt (bf16), E = e^Gamma into sG (in place) and global
  {
    const ushort* vp0 = (const ushort*)&v0;
    const ushort* vp1 = (const ushort*)&v1;
    float ebuf[16];
#pragma unroll
    for (int i = 0; i < 16; ++i) {
      float G = sG[r * SGS + c0 + i];
      float en = expf(-G);
      float ep = expf(G);
      float vv = bf2f(i < 8 ? vp0[i] : vp1[i - 8]);
      sVt[(c0 + i) * SP + r] = f2bf(vv * en);
      sG[r * SGS + c0 + i] = ep;
      ebuf[i] = ep;
    }
#pragma unroll
    for (int m = 0; m < 4; ++m)
      *(float4*)(gate + gb + m * 4) =
          make_float4(ebuf[m * 4], ebuf[m * 4 + 1], ebuf[m * 4 + 2], ebuf[m * 4 + 3]);
  }
  __syncthreads();

  if (tid < 64)
    Lam[(size_t)(bh * NCHUNK + c) * HDIM + tid] = sG[63 * SGS + tid];

  // scores = tril(Q K^T) -> sA (bf16)
  {
    floatx4 acc[2][2];
#pragma unroll
    for (int i = 0; i < 2; ++i)
#pragma unroll
      for (int j = 0; j < 2; ++j) acc[i][j] = (floatx4){0.f, 0.f, 0.f, 0.f};
#pragma unroll
    for (int ks = 0; ks < 2; ++ks) {
      short8 a[2], bb[2];
#pragma unroll
      for (int i = 0; i < 2; ++i)
        a[i] = *(const short8*)&sQ[(wm2 + i * 16 + fm) * SP + ks * 32 + quad * 8];
#pragma unroll
      for (int j = 0; j < 2; ++j)
        bb[j] = *(const short8*)&sK[(wn2 + j * 16 + fm) * SP + ks * 32 + quad * 8];
#pragma unroll
      for (int i = 0; i < 2; ++i)
#pragma unroll
        for (int j = 0; j < 2; ++j)
          acc[i][j] = __builtin_amdgcn_mfma_f32_16x16x32_bf16(a[i], bb[j],
                                                              acc[i][j], 0, 0, 0);
    }
#pragma unroll
    for (int i = 0; i < 2; ++i)
#pragma unroll
      for (int j = 0; j < 2; ++j) {
        const int t0 = wm2 + i * 16 + quad * 4;
        const int s = wn2 + j * 16 + fm;
#pragma unroll
        for (int rr = 0; rr < 4; ++rr) {
          float val = (s <= t0 + rr) ? acc[i][j][rr] : 0.f;
          sA[(t0 + rr) * SP + s] = f2bf(val);
        }
      }
  }
  __syncthreads();

  // out_intra = E . (sA @ V~)   and   Sdelta = Lam . (V~^T K)
  {
    floatx4 accO[2][2], accD[2][2];
#pragma unroll
    for (int i = 0; i < 2; ++i)
#pragma unroll
      for (int j = 0; j < 2; ++j) {
        accO[i][j] = (floatx4){0.f, 0.f, 0.f, 0.f};
        accD[i][j] = (floatx4){0.f, 0.f, 0.f, 0.f};
      }
#pragma unroll
    for (int ks = 0; ks < 2; ++ks) {
      short8 aa[2], bv[2], av[2], bk[2];
#pragma unroll
      for (int i = 0; i < 2; ++i) {
        aa[i] = *(const short8*)&sA[(wm2 + i * 16 + fm) * SP + ks * 32 + quad * 8];
        av[i] = *(const short8*)&sVt[(wm2 + i * 16 + fm) * SP + ks * 32 + quad * 8];
      }
#pragma unroll
      for (int j = 0; j < 2; ++j) {
        bv[j] = *(const short8*)&sVt[(wn2 + j * 16 + fm) * SP + ks * 32 + quad * 8];
        bk[j] = *(const short8*)&sKt[(wn2 + j * 16 + fm) * SP + ks * 32 + quad * 8];
      }
#pragma unroll
      for (int i = 0; i < 2; ++i)
#pragma unroll
        for (int j = 0; j < 2; ++j) {
          accO[i][j] = __builtin_amdgcn_mfma_f32_16x16x32_bf16(aa[i], bv[j],
                                                               accO[i][j], 0, 0, 0);
          accD[i][j] = __builtin_amdgcn_mfma_f32_16x16x32_bf16(av[i], bk[j],
                                                               accD[i][j], 0, 0, 0);
        }
    }
    const size_t sbase = (size_t)(bh * NCHUNK + c) * (HDIM * HDIM);
#pragma unroll
    for (int i = 0; i < 2; ++i)
#pragma unroll
      for (int j = 0; j < 2; ++j) {
        const int m0 = wm2 + i * 16 + quad * 4;
        const int n = wn2 + j * 16 + fm;
#pragma unroll
        for (int rr = 0; rr < 4; ++rr) {
          const int m = m0 + rr;
          att[base + (size_t)m * HIDS + n] = accO[i][j][rr] * sG[m * SGS + n];
          Sdelta[sbase + (size_t)m * HDIM + n] = accD[i][j][rr] * sG[63 * SGS + m];
        }
      }
  }
}

// ---------------------------------------------------------------------------
// Phase 2a: sequential over 32 chunk boundaries; 32 blocks, state in regs.
// ---------------------------------------------------------------------------
__global__ __launch_bounds__(256) void state_scan_kernel(
    const float* __restrict__ Sdelta, const float* __restrict__ Lam,
    float* __restrict__ Sprev) {
  const int bh = blockIdx.x;
  const int tid = threadIdx.x;
  float S[16];
#pragma unroll
  for (int i = 0; i < 16; ++i) S[i] = 0.f;

  float pd[16], pl[16];
  {
    const size_t base = (size_t)(bh * NCHUNK) * (HDIM * HDIM);
    const size_t lbase = (size_t)(bh * NCHUNK) * HDIM;
#pragma unroll
    for (int i = 0; i < 16; ++i) {
      int e = tid + 256 * i;
      pd[i] = Sdelta[base + e];
      pl[i] = Lam[lbase + (e >> 6)];
    }
  }
  for (int c = 0; c < NCHUNK; ++c) {
    float cd[16], cl[16];
#pragma unroll
    for (int i = 0; i < 16; ++i) { cd[i] = pd[i]; cl[i] = pl[i]; }
    if (c + 1 < NCHUNK) {
      const size_t base = (size_t)(bh * NCHUNK + c + 1) * (HDIM * HDIM);
      const size_t lbase = (size_t)(bh * NCHUNK + c + 1) * HDIM;
#pragma unroll
      for (int i = 0; i < 16; ++i) {
        int e = tid + 256 * i;
        pd[i] = Sdelta[base + e];
        pl[i] = Lam[lbase + (e >> 6)];
      }
    }
    const size_t obase = (size_t)(bh * NCHUNK + c) * (HDIM * HDIM);
#pragma unroll
    for (int i = 0; i < 16; ++i) {
      int e = tid + 256 * i;
      Sprev[obase + e] = S[i];
      S[i] = fmaf(S[i], cl[i], cd[i]);
    }
  }
}

// ---------------------------------------------------------------------------
// Phase 2b (MFMA): att[t,v] += E[t,v] * sum_k q[t,k] * Sprev[v,k]
// ---------------------------------------------------------------------------
__global__ __launch_bounds__(256) void chunk_out_kernel(
    const ushort* __restrict__ q, const float* __restrict__ E,
    const float* __restrict__ Sprev, float* __restrict__ att) {
  const int bid = blockIdx.x;
  const int c = bid & 31, bh = bid >> 5;
  const int b = bh >> 4, h = bh & 15;
  const int tid = threadIdx.x;
  const int lane = tid & 63, wave = tid >> 6;
  const int fm = lane & 15, quad = lane >> 4;
  const int wm2 = (wave >> 1) * 32, wn2 = (wave & 1) * 32;

  __shared__ ushort sQ2[64 * SP];
  __shared__ ushort sS[64 * SP];

  const size_t base = ((size_t)b * LSEQ + (size_t)c * CHUNK) * HIDS + (size_t)h * HDIM;
  const size_t sbase = (size_t)(bh * NCHUNK + c) * (HDIM * HDIM);
  const int r = tid >> 2, c0 = (tid & 3) * 16;
  const size_t gb = base + (size_t)r * HIDS + c0;

  short8 q0 = *(const short8*)(q + gb), q1 = *(const short8*)(q + gb + 8);
  *(short8*)&sQ2[r * SP + c0] = q0;
  *(short8*)&sQ2[r * SP + c0 + 8] = q1;
  {
    const float* sp = Sprev + sbase + (size_t)r * HDIM + c0;
    float4 s0 = *(const float4*)(sp);
    float4 s1 = *(const float4*)(sp + 4);
    float4 s2 = *(const float4*)(sp + 8);
    float4 s3 = *(const float4*)(sp + 12);
    ushort* d = &sS[r * SP + c0];
    d[0] = f2bf(s0.x); d[1] = f2bf(s0.y); d[2] = f2bf(s0.z); d[3] = f2bf(s0.w);
    d[4] = f2bf(s1.x); d[5] = f2bf(s1.y); d[6] = f2bf(s1.z); d[7] = f2bf(s1.w);
    d[8] = f2bf(s2.x); d[9] = f2bf(s2.y); d[10] = f2bf(s2.z); d[11] = f2bf(s2.w);
    d[12] = f2bf(s3.x); d[13] = f2bf(s3.y); d[14] = f2bf(s3.z); d[15] = f2bf(s3.w);
  }
  __syncthreads();

  floatx4 acc[2][2];
#pragma unroll
  for (int i = 0; i < 2; ++i)
#pragma unroll
    for (int j = 0; j < 2; ++j) acc[i][j] = (floatx4){0.f, 0.f, 0.f, 0.f};
#pragma unroll
  for (int ks = 0; ks < 2; ++ks) {
    short8 a[2], bb[2];
#pragma unroll
    for (int i = 0; i < 2; ++i)
      a[i] = *(const short8*)&sQ2[(wm2 + i * 16 + fm) * SP + ks * 32 + quad * 8];
#pragma unroll
    for (int j = 0; j < 2; ++j)
      bb[j] = *(const short8*)&sS[(wn2 + j * 16 + fm) * SP + ks * 32 + quad * 8];
#pragma unroll
    for (int i = 0; i < 2; ++i)
#pragma unroll
      for (int j = 0; j < 2; ++j)
        acc[i][j] = __builtin_amdgcn_mfma_f32_16x16x32_bf16(a[i], bb[j],
                                                            acc[i][j], 0, 0, 0);
  }
#pragma unroll
  for (int i = 0; i < 2; ++i)
#pragma unroll
    for (int j = 0; j < 2; ++j) {
      const int m0 = wm2 + i * 16 + quad * 4;
      const int n = wn2 + j * 16 + fm;
#pragma unroll
      for (int rr = 0; rr < 4; ++rr) {
        const size_t idx = base + (size_t)(m0 + rr) * HIDS + n;
        att[idx] = fmaf(acc[i][j][rr], E[idx], att[idx]);
      }
    }
}

// ---------------------------------------------------------------------------
// y = (LayerNorm(att) * gamma + beta) * silu(g), bf16 out. g is bf16.
// ---------------------------------------------------------------------------
__global__ __launch_bounds__(256) void ln_gate_kernel(const float* __restrict__ att,
                                                      const ushort* __restrict__ g,
                                                      const float* __restrict__ gamma,
                                                      const float* __restrict__ beta,
                                                      ushort* __restrict__ ybf) {
  const int row = blockIdx.x;
  const int tid = threadIdx.x;
  const float* ar = att + (size_t)row * HIDS;
  float4 a = *(const float4*)(ar + tid * 4);
  float s = a.x + a.y + a.z + a.w;
  float ss = a.x * a.x + a.y * a.y + a.z * a.z + a.w * a.w;
#pragma unroll
  for (int off = 32; off; off >>= 1) {
    s += __shfl_down(s, off);
    ss += __shfl_down(ss, off);
  }
  __shared__ float rs[4], rss[4];
  const int wid = tid >> 6;
  if ((tid & 63) == 0) { rs[wid] = s; rss[wid] = ss; }
  __syncthreads();
  const float mean = (rs[0] + rs[1] + rs[2] + rs[3]) * (1.f / HIDS);
  const float ex2 = (rss[0] + rss[1] + rss[2] + rss[3]) * (1.f / HIDS);
  const float rstd = rsqrtf(ex2 - mean * mean + 1e-5f);

  float4 ga = *(const float4*)(gamma + tid * 4);
  float4 be = *(const float4*)(beta + tid * 4);
  ushort4 gu = *(const ushort4*)(g + (size_t)row * HIDS + tid * 4);
  float gx = bf2f(gu.x), gy = bf2f(gu.y), gz = bf2f(gu.z), gw = bf2f(gu.w);
  float4 o;
  o.x = ((a.x - mean) * rstd * ga.x + be.x) * (gx / (1.f + expf(-gx)));
  o.y = ((a.y - mean) * rstd * ga.y + be.y) * (gy / (1.f + expf(-gy)));
  o.z = ((a.z - mean) * rstd * ga.z + be.z) * (gz / (1.f + expf(-gz)));
  o.w = ((a.w - mean) * rstd * ga.w + be.w) * (gw / (1.f + expf(-gw)));
  ushort4 ob;
  ob.x = f2bf(o.x); ob.y = f2bf(o.y); ob.z = f2bf(o.z); ob.w = f2bf(o.w);
  *(ushort4*)(ybf + (size_t)row * HIDS + tid * 4) = ob;
}

// ---------------------------------------------------------------------------
extern "C" void kernel_launch(void* const* d_in, const int* in_sizes, int n_in,
                              void* d_out, int out_size, void* d_ws, size_t ws_size,
                              hipStream_t stream) {
  const float* x     = (const float*)d_in[0];
  const float* Wq    = (const float*)d_in[1];
  const float* Wk    = (const float*)d_in[2];
  const float* Wv    = (const float*)d_in[3];
  const float* Wg    = (const float*)d_in[4];
  const float* Wgk1  = (const float*)d_in[5];
  const float* Wgk2  = (const float*)d_in[6];
  const float* bgk2  = (const float*)d_in[7];
  const float* gamma = (const float*)d_in[8];
  const float* beta  = (const float*)d_in[9];
  const float* Wout  = (const float*)d_in[10];
  float* out = (float*)d_out;

  const size_t SZ = (size_t)NROW * HIDS;  // 4M elements
  float* ws = (float*)d_ws;
  float* attb   = ws;                 // 4M f
  float* gateb  = ws + SZ;            // 4M f (logg -> E)
  float* Sdelta = ws + 2 * SZ;        // 4M f
  float* Sprevb = ws + 3 * SZ;        // 4M f
  float* Lamb   = ws + 4 * SZ;        // 64K f
  ushort* qbf = (ushort*)(ws + 4 * SZ + 65536);
  ushort* kbf = qbf + SZ;
  ushort* vbf = kbf + SZ;
  ushort* gbf = vbf + SZ;
  ushort* xbf = gbf + SZ;
  ushort* Wtq = xbf + SZ;
  ushort* Wtk = Wtq + HIDS * HIDS;
  ushort* Wtv = Wtk + HIDS * HIDS;
  ushort* Wtg = Wtv + HIDS * HIDS;
  ushort* Wto = Wtg + HIDS * HIDS;
  ushort* ybf = vbf;  // vbf dead after chunk_local

  cvt_x_kernel<<<SZ / 1024, 256, 0, stream>>>(x, xbf);
  transpose_w_kernel<<<dim3(16, 16, 5), 256, 0, stream>>>(
      Wq, Wk, Wv, Wg, Wout, Wtq, Wtk, Wtv, Wtg, Wto);

  proj4_kernel<<<dim3(HIDS / 128, NROW / 128, 4), 256, 0, stream>>>(
      xbf, Wtq, Wtk, Wtv, Wtg, qbf, kbf, vbf, gbf);
  gate_kernel<<<NROW, 256, 0, stream>>>(x, Wgk1, Wgk2, bgk2, gateb);

  chunk_local_kernel<<<BBATCH * NHEAD * NCHUNK, 256, 0, stream>>>(
      qbf, kbf, vbf, gateb, attb, Sdelta, Lamb);
  state_scan_kernel<<<BBATCH * NHEAD, 256, 0, stream>>>(Sdelta, Lamb, Sprevb);
  chunk_out_kernel<<<BBATCH * NHEAD * NCHUNK, 256, 0, stream>>>(
      qbf, gateb, Sprevb, attb);

  ln_gate_kernel<<<NROW, 256, 0, stream>>>(attb, gbf, gamma, beta, ybf);
  gemm_out_kernel<<<dim3(HIDS / 64, NROW / 128), 256, 0, stream>>>(ybf, Wto, out);
}